// Round 3
// baseline (33.002 us; speedup 1.0000x reference)
//
#include <hip/hip_runtime.h>
#include <math.h>

// PolyaTree: per (point, dim) descend an L=8 complete binary tree (255 nodes),
// result = mean_d( sum_path log(b) - log(leaf_len) ).
//
// Strategy: the per-dim result is piecewise-constant in x over 128 leaf
// intervals. Precompute (bit-exact vs numpy: plain mul+add, contract off):
//   split_lut[d][node]  for the 127 internal/branching nodes (levels 0..6)
//   value_lut[d][leaf]  = sum_path log(b) - log(leaf_len)   (128 leaves)
// Hot kernel: 7 LDS compares + 1 LDS value fetch per (point,dim). No logs.

constexpr int DIMS     = 16;
constexpr int NODES    = 255;   // 2^8 - 1
constexpr int INTERNAL = 127;   // nodes used for branching (levels 0..6)
constexpr int LSTRIDE  = 128;   // per-dim LUT stride

__global__ void build_luts(const float* __restrict__ samples, // (16, 255)
                           float* __restrict__ split_lut,     // (16, 128)
                           float* __restrict__ value_lut)     // (16, 128)
{
#pragma clang fp contract(off)
    int t = blockIdx.x * blockDim.x + threadIdx.x;
    if (t >= DIMS * NODES) return;
    int d = t / NODES;
    int j = t - d * NODES;              // full-tree node index 0..254
    const float* s = samples + d * NODES;

    unsigned key = (unsigned)(j + 1);   // binary: 1 then path bits (0=left)
    int level = 31 - __clz(key);        // 0..7
    float lo = 0.0f, hi = 1.0f, acc = 0.0f;
    int i = 0;
    for (int tb = level - 1; tb >= 0; --tb) {
        float b = s[i];
        acc += logf(b);                 // visited-node log(b) (leaf path use)
        float len = hi - lo;
        float split = lo + b * len;     // EXACT mirror of reference (no fma)
        unsigned bit = (key >> tb) & 1u;
        if (bit == 0u) {
            hi = split;
        } else {
            lo = split;
            hi = split + (1.0f - b) * len;
        }
        i = 2 * i + 1 + (int)bit;
    }
    // now i == j; (lo,hi) is node j's interval, bit-exact vs compute_intervals
    float b = s[j];
    if (j < INTERNAL) {
        float len = hi - lo;
        split_lut[d * LSTRIDE + j] = lo + b * len;
    } else {
        acc += logf(b);                 // leaf node's own log(b) (l = L-1 term)
        value_lut[d * LSTRIDE + (j - INTERNAL)] = acc - logf(hi - lo);
    }
}

__global__ __launch_bounds__(256) void polya_eval(
    const float* __restrict__ x,          // (n, 16) row-major
    const float* __restrict__ split_lut,  // (16*128)
    const float* __restrict__ value_lut,  // (16*128)
    float* __restrict__ out,
    int n)
{
    __shared__ float s_split[DIMS * LSTRIDE];   // 8 KB
    __shared__ float s_value[DIMS * LSTRIDE];   // 8 KB
    for (int i = threadIdx.x; i < DIMS * LSTRIDE; i += 256) {
        s_split[i] = split_lut[i];
        s_value[i] = value_lut[i];
    }
    __syncthreads();

    const int stride = gridDim.x * 256;
    for (int p = blockIdx.x * 256 + threadIdx.x; p < n; p += stride) {
        const float4* xr = reinterpret_cast<const float4*>(x + (size_t)p * DIMS);
        float4 a = xr[0], b4 = xr[1], c = xr[2], e = xr[3];
        float xs[DIMS] = {a.x, a.y, a.z, a.w,  b4.x, b4.y, b4.z, b4.w,
                          c.x, c.y, c.z, c.w,  e.x,  e.y,  e.z,  e.w};
        float acc = 0.0f;
#pragma unroll
        for (int d = 0; d < DIMS; ++d) {
            const float xv = xs[d];
            int idx = 0;
#pragma unroll
            for (int l = 0; l < 7; ++l) {
                float sp = s_split[d * LSTRIDE + idx];
                // reference: x <= split -> left child (2i+1), else right (2i+2)
                idx = 2 * idx + 1 + (int)(xv > sp);
            }
            acc += s_value[d * LSTRIDE + (idx - INTERNAL)];
        }
        out[p] = acc * 0.0625f;   // mean over 16 dims (exact /16)
    }
}

extern "C" void kernel_launch(void* const* d_in, const int* in_sizes, int n_in,
                              void* d_out, int out_size, void* d_ws, size_t ws_size,
                              hipStream_t stream) {
    const float* x       = (const float*)d_in[0];   // (n,16) f32
    const float* samples = (const float*)d_in[1];   // (16,255) f32
    // d_in[2] is L == 8 (structure hard-coded / fully unrolled)
    float* out = (float*)d_out;
    const int n = in_sizes[0] / DIMS;

    float* split_lut = (float*)d_ws;                 // 16*128 f32
    float* value_lut = split_lut + DIMS * LSTRIDE;   // 16*128 f32 (16 KB total)

    build_luts<<<(DIMS * NODES + 255) / 256, 256, 0, stream>>>(samples, split_lut, value_lut);

    int blocks = (n + 255) / 256;
    if (blocks > 2048) blocks = 2048;
    polya_eval<<<blocks, 256, 0, stream>>>(x, split_lut, value_lut, out, n);
}